// Round 1
// baseline (880.921 us; speedup 1.0000x reference)
//
#include <hip/hip_runtime.h>
#include <math.h>

#define Bz 16
#define Lz 20
#define DTz 768
#define Cz 256

// workspace layout (float element offsets)
#define WS_QK   0          // B*L*C = 81920
#define WS_V    81920      // B*L*C = 81920
#define WS_G    163840     // B*L*L = 6400
#define WS_OPG  170240     // B*C (1+gamma)
#define WS_BETA 174336     // B*C
#define WS_VEC2 178432     // B*2
#define WS_GMAX 178464     // B*4 (float bits via uint atomicMax)
#define WS_GATE 178528     // B*21760 raw gate norms
// total 526688 floats = 2.06 MB

// ---------------------------------------------------------------- P1: K,V,QK
// grid 160 = B * (L/2), block 256. QK[b,l,c] = (1/16) * sum_o K[b,l,o]*Wq[o,c]
__global__ __launch_bounds__(256) void k_prep1(
    const float* __restrict__ wt, const float* __restrict__ Wk,
    const float* __restrict__ Wv, const float* __restrict__ Wq,
    float* __restrict__ ws) {
  __shared__ __align__(16) float wtT[DTz * 2];   // [d][2]
  __shared__ __align__(16) float Klds[Cz * 2];   // [o][2]
  const int bl = blockIdx.x;
  const int b = bl / (Lz / 2);
  const int l0 = (bl % (Lz / 2)) * 2;
  const int tid = threadIdx.x;
  for (int i = tid; i < 2 * DTz; i += 256) {
    const int lp = i / DTz, d = i - lp * DTz;
    wtT[d * 2 + lp] = wt[(b * Lz + l0 + lp) * DTz + d];
  }
  __syncthreads();
  const int o = tid;
  float k0 = 0.f, k1 = 0.f, v0 = 0.f, v1 = 0.f;
  for (int d = 0; d < DTz; ++d) {
    const float2 w2 = *(const float2*)&wtT[d * 2];
    const float wk = Wk[d * Cz + o];
    const float wv = Wv[d * Cz + o];
    k0 = fmaf(w2.x, wk, k0); k1 = fmaf(w2.y, wk, k1);
    v0 = fmaf(w2.x, wv, v0); v1 = fmaf(w2.y, wv, v1);
  }
  ws[WS_V + (b * Lz + l0) * Cz + o] = v0;
  ws[WS_V + (b * Lz + l0 + 1) * Cz + o] = v1;
  Klds[o * 2] = k0; Klds[o * 2 + 1] = k1;
  __syncthreads();
  const int c = tid;
  float q0 = 0.f, q1 = 0.f;
  for (int oo = 0; oo < Cz; ++oo) {
    const float2 kk = *(const float2*)&Klds[oo * 2];
    const float wq = Wq[oo * Cz + c];
    q0 = fmaf(kk.x, wq, q0); q1 = fmaf(kk.y, wq, q1);
  }
  ws[WS_QK + (b * Lz + l0) * Cz + c] = q0 * 0.0625f;     // /sqrt(256)
  ws[WS_QK + (b * Lz + l0 + 1) * Cz + c] = q1 * 0.0625f;
}

// ------------------------------------------- P2: Gram, gamma, beta, vec2, gmax=0
// grid (16, 4): y = task (0 gram, 1 gamma, 2 beta, 3 vec2+zero)
__global__ __launch_bounds__(256) void k_prep2(
    const float* __restrict__ sv_in,
    const float* __restrict__ g_w1, const float* __restrict__ g_b1,
    const float* __restrict__ g_w2, const float* __restrict__ g_b2,
    const float* __restrict__ b_w1, const float* __restrict__ b_b1,
    const float* __restrict__ b_w2, const float* __restrict__ b_b2,
    const float* __restrict__ d_w1, const float* __restrict__ d_b1,
    const float* __restrict__ d_w2, const float* __restrict__ d_b2,
    float* __restrict__ ws) {
  const int b = blockIdx.x, task = blockIdx.y, tid = threadIdx.x;
  __shared__ __align__(16) float sh[Lz * 257];  // 5140 floats, reused per task
  if (task == 0) {
    // Gram G[l,lp] = V_l . V_lp   (padded stride 257 to dodge bank conflicts)
    for (int i = tid; i < Lz * Cz; i += 256) {
      const int l = i >> 8, o = i & 255;
      sh[l * 257 + o] = ws[WS_V + b * Lz * Cz + i];
    }
    __syncthreads();
    for (int t = tid; t < Lz * Lz; t += 256) {
      const int l = t / Lz, lp = t - l * Lz;
      float s = 0.f;
      for (int o = 0; o < Cz; ++o) s = fmaf(sh[l * 257 + o], sh[lp * 257 + o], s);
      ws[WS_G + b * Lz * Lz + t] = s;
    }
  } else if (task == 3) {
    for (int i = tid; i < DTz; i += 256) sh[i] = sv_in[b * DTz + i];
    __syncthreads();
    if (tid < 64) {
      float x = d_b1[tid];
      for (int d = 0; d < DTz; ++d) x = fmaf(sh[d], d_w1[d * 64 + tid], x);
      sh[DTz + tid] = fmaxf(x, 0.f);
    }
    __syncthreads();
    if (tid == 0) {
      float v0 = d_b2[0], v1 = d_b2[1];
      for (int j = 0; j < 64; ++j) {
        v0 = fmaf(sh[DTz + j], d_w2[2 * j], v0);
        v1 = fmaf(sh[DTz + j], d_w2[2 * j + 1], v1);
      }
      const float nr = fmaxf(sqrtf(v0 * v0 + v1 * v1), 1e-12f);
      ws[WS_VEC2 + 2 * b] = v0 / nr;
      ws[WS_VEC2 + 2 * b + 1] = v1 / nr;
      unsigned* gm = (unsigned*)&ws[WS_GMAX];
      gm[4 * b] = 0u; gm[4 * b + 1] = 0u; gm[4 * b + 2] = 0u; gm[4 * b + 3] = 0u;
    }
  } else {
    const float* w1 = (task == 1) ? g_w1 : b_w1;
    const float* b1 = (task == 1) ? g_b1 : b_b1;
    const float* w2 = (task == 1) ? g_w2 : b_w2;
    const float* b2 = (task == 1) ? g_b2 : b_b2;
    for (int i = tid; i < DTz; i += 256) sh[i] = sv_in[b * DTz + i];
    __syncthreads();
    float a = b1[tid];
    for (int d = 0; d < DTz; ++d) a = fmaf(sh[d], w1[d * Cz + tid], a);
    sh[DTz + tid] = fmaxf(a, 0.f);
    __syncthreads();
    float r = b2[tid];
    for (int cp = 0; cp < Cz; ++cp) r = fmaf(sh[DTz + cp], w2[cp * Cz + tid], r);
    ws[((task == 1) ? WS_OPG : WS_BETA) + b * Cz + tid] =
        (task == 1) ? (1.0f + r) : r;
  }
}

// ---------------------------------------------------------------- gate pass
// grid 1360: lvl0 [0,1024) lvl1 [1024,1280) lvl2 [1280,1344) lvl3 [1344,1360)
__global__ __launch_bounds__(256) void k_gate(
    const float* __restrict__ f0, const float* __restrict__ f1,
    const float* __restrict__ f2, const float* __restrict__ f3,
    const int* __restrict__ mask, float* __restrict__ ws) {
  __shared__ __align__(16) float qkt[Cz * Lz];  // [c][l], rows of 20 (80B, 16B-aligned)
  __shared__ __align__(16) float gl[Lz * Lz];   // [l][lp]
  __shared__ float red[256];
  __shared__ int msk[Lz];
  const int bx = blockIdx.x;
  int lvl, b, tile, N;
  const float* F;
  if (bx < 1024)      { lvl = 0; N = 16384; F = f0; b = bx >> 6; tile = bx & 63; }
  else if (bx < 1280) { const int r = bx - 1024; lvl = 1; N = 4096; F = f1; b = r >> 4; tile = r & 15; }
  else if (bx < 1344) { const int r = bx - 1280; lvl = 2; N = 1024; F = f2; b = r >> 2; tile = r & 3; }
  else                { const int r = bx - 1344; lvl = 3; N = 256;  F = f3; b = r;      tile = 0; }
  const int goff_[4] = {0, 262144, 327680, 344064};
  const int tid = threadIdx.x;
  for (int i = tid; i < Cz * Lz; i += 256) {
    const int l = i >> 8, cc = i & 255;
    qkt[cc * Lz + l] = ws[WS_QK + (b * Lz + l) * Cz + cc];
  }
  for (int i = tid; i < Lz * Lz; i += 256) gl[i] = ws[WS_G + b * Lz * Lz + i];
  if (tid < Lz) msk[tid] = mask[b * Lz + tid];
  __syncthreads();

  const int n = tile * 256 + tid;
  const float* fp = F + (size_t)(b * Cz) * N + n;
  float acc[Lz];
#pragma unroll
  for (int l = 0; l < Lz; ++l) acc[l] = 0.f;
#pragma unroll 4
  for (int cc = 0; cc < Cz; ++cc) {
    const float f = fp[(size_t)cc * N];
    const float4* q4 = (const float4*)&qkt[cc * Lz];
#pragma unroll
    for (int j = 0; j < 5; ++j) {
      const float4 q = q4[j];
      acc[j * 4 + 0] = fmaf(f, q.x, acc[j * 4 + 0]);
      acc[j * 4 + 1] = fmaf(f, q.y, acc[j * 4 + 1]);
      acc[j * 4 + 2] = fmaf(f, q.z, acc[j * 4 + 2]);
      acc[j * 4 + 3] = fmaf(f, q.w, acc[j * 4 + 3]);
    }
  }
  // masked softmax weights (unnormalized)
  float m = -1e30f;
#pragma unroll
  for (int l = 0; l < Lz; ++l) if (msk[l]) m = fmaxf(m, acc[l]);
  float e[Lz];
  float s = 0.f;
#pragma unroll
  for (int l = 0; l < Lz; ++l) {
    e[l] = msk[l] ? __expf(acc[l] - m) : 0.f;
    s += e[l];
  }
  // gate = ||attn @ V|| = sqrt(e^T G e) / s
  float q = 0.f;
#pragma unroll
  for (int l = 0; l < Lz; ++l) {
    const float4* g4 = (const float4*)&gl[l * Lz];
    float t = 0.f;
#pragma unroll
    for (int j = 0; j < 5; ++j) {
      const float4 g = g4[j];
      t = fmaf(g.x, e[j * 4 + 0], t);
      t = fmaf(g.y, e[j * 4 + 1], t);
      t = fmaf(g.z, e[j * 4 + 2], t);
      t = fmaf(g.w, e[j * 4 + 3], t);
    }
    q = fmaf(e[l], t, q);
  }
  const float gate = sqrtf(fmaxf(q, 0.f)) / s;
  ws[WS_GATE + goff_[lvl] + b * N + n] = gate;
  // block max then one atomic (gate >= 0 so uint compare == float compare)
  red[tid] = gate;
  __syncthreads();
  for (int st = 128; st > 0; st >>= 1) {
    if (tid < st) red[tid] = fmaxf(red[tid], red[tid + st]);
    __syncthreads();
  }
  if (tid == 0)
    atomicMax((unsigned*)&ws[WS_GMAX] + (b * 4 + lvl), __float_as_uint(red[0]));
}

// ---------------------------------------------------------------- modulation
// grid 352 = 16 b * 22 tiles (1024 positions/tile). float4 streaming.
__global__ __launch_bounds__(256) void k_mod(
    const float* __restrict__ f0, const float* __restrict__ f1,
    const float* __restrict__ f2, const float* __restrict__ f3,
    const float* __restrict__ ws, float* __restrict__ out) {
  __shared__ float opg[Cz];
  __shared__ float bet[Cz];
  const int bx = blockIdx.x;
  const int b = bx / 22, tl = bx - b * 22;
  int lvl, tile;
  if (tl < 16)      { lvl = 0; tile = tl; }
  else if (tl < 20) { lvl = 1; tile = tl - 16; }
  else if (tl == 20){ lvl = 2; tile = 0; }
  else              { lvl = 3; tile = 0; }
  const int Ntab[4]  = {16384, 4096, 1024, 256};
  const int lwtab[4] = {7, 6, 5, 4};
  const int goff_[4] = {0, 262144, 327680, 344064};
  const long long moff_[4] = {0LL, 67108864LL, 83886080LL, 88080384LL};
  const long long gout_[4] = {89128960LL, 89391104LL, 89456640LL, 89473024LL};
  const int N = Ntab[lvl], lw = lwtab[lvl], W = 1 << lw;
  const float* F = (lvl == 0) ? f0 : (lvl == 1) ? f1 : (lvl == 2) ? f2 : f3;
  const int tid = threadIdx.x;
  opg[tid] = ws[WS_OPG + b * Cz + tid];
  bet[tid] = ws[WS_BETA + b * Cz + tid];
  __syncthreads();
  const int n0 = tile * 1024 + tid * 4;
  if (n0 >= N) return;  // only trims lvl3; no barriers after this point
  const float gmax = ws[WS_GMAX + b * 4 + lvl];  // bits stored = float bits
  const float gscale = 1.0f / (gmax + 1e-6f);
  const float v0 = ws[WS_VEC2 + 2 * b], v1 = ws[WS_VEC2 + 2 * b + 1];
  const float4 g4 = *(const float4*)&ws[WS_GATE + goff_[lvl] + b * N + n0];
  const float istep = 2.0f / (float)(W - 1);  // H == W at every level
  const int h = n0 >> lw;
  const float py = v1 * (-1.0f + (float)h * istep);
  float gi[4];
  const float gv[4] = {g4.x, g4.y, g4.z, g4.w};
#pragma unroll
  for (int j = 0; j < 4; ++j) {
    const int w = (n0 + j) & (W - 1);
    const float p = fmaf(v0, -1.0f + (float)w * istep, py);
    const float di = 1.0f / (1.0f + __expf(-p));
    gi[j] = gv[j] * gscale * di;
  }
  *(float4*)&out[gout_[lvl] + b * N + n0] = make_float4(gi[0], gi[1], gi[2], gi[3]);
  const float* fp = F + (size_t)(b * Cz) * N + n0;
  float* op = out + moff_[lvl] + (size_t)(b * Cz) * N + n0;
#pragma unroll 4
  for (int cc = 0; cc < Cz; ++cc) {
    const float4 f4 = *(const float4*)&fp[(size_t)cc * N];
    const float og = opg[cc], bb = bet[cc];
    float4 o4;
    o4.x = fmaf(f4.x, gi[0] * og, bb);
    o4.y = fmaf(f4.y, gi[1] * og, bb);
    o4.z = fmaf(f4.z, gi[2] * og, bb);
    o4.w = fmaf(f4.w, gi[3] * og, bb);
    *(float4*)&op[(size_t)cc * N] = o4;
  }
}

extern "C" void kernel_launch(void* const* d_in, const int* in_sizes, int n_in,
                              void* d_out, int out_size, void* d_ws, size_t ws_size,
                              hipStream_t stream) {
  const float* f0   = (const float*)d_in[0];
  const float* f1   = (const float*)d_in[1];
  const float* f2   = (const float*)d_in[2];
  const float* f3   = (const float*)d_in[3];
  const float* wt   = (const float*)d_in[4];
  const float* sv   = (const float*)d_in[5];
  const int*   amsk = (const int*)d_in[6];
  const float* Wq   = (const float*)d_in[7];
  const float* Wk   = (const float*)d_in[8];
  const float* Wv   = (const float*)d_in[9];
  const float* g_w1 = (const float*)d_in[10];
  const float* g_b1 = (const float*)d_in[11];
  const float* g_w2 = (const float*)d_in[12];
  const float* g_b2 = (const float*)d_in[13];
  const float* b_w1 = (const float*)d_in[14];
  const float* b_b1 = (const float*)d_in[15];
  const float* b_w2 = (const float*)d_in[16];
  const float* b_b2 = (const float*)d_in[17];
  const float* d_w1 = (const float*)d_in[18];
  const float* d_b1 = (const float*)d_in[19];
  const float* d_w2 = (const float*)d_in[20];
  const float* d_b2 = (const float*)d_in[21];
  float* ws = (float*)d_ws;
  float* out = (float*)d_out;

  k_prep1<<<Bz * (Lz / 2), 256, 0, stream>>>(wt, Wk, Wv, Wq, ws);
  k_prep2<<<dim3(Bz, 4), 256, 0, stream>>>(sv, g_w1, g_b1, g_w2, g_b2,
                                           b_w1, b_b1, b_w2, b_b2,
                                           d_w1, d_b1, d_w2, d_b2, ws);
  k_gate<<<1360, 256, 0, stream>>>(f0, f1, f2, f3, amsk, ws);
  k_mod<<<Bz * 22, 256, 0, stream>>>(f0, f1, f2, f3, ws, out);
}